// Round 3
// baseline (827.143 us; speedup 1.0000x reference)
//
#include <hip/hip_runtime.h>

// Problem constants (from reference setup_inputs / OUT_H, OUT_W)
#define BATCH  16
#define HIN    384
#define WIN    384
#define CH     64
#define OUTH   224
#define OUTW   224

// Tile: 2 output rows x 32 output cols = 64 pixels.
// 7 col-tiles x 112 row-pairs = 784 tiles/img; 4 tiles per block -> 196 blocks/img.
// Grid shrinks 50176 -> 3136 blocks (16x): tests the block-turnover-limit theory,
// and gives each thread 4 pixels = 16 independent global loads in flight.
#define TILE_COLS 32
#define COLTILES  (OUTW / TILE_COLS)                      // 7
#define ROWPAIRS  (OUTH / 2)                              // 112
#define TILES_PER_IMG (COLTILES * ROWPAIRS)               // 784
#define TILES_PER_BLOCK 4
#define BLOCKS_PER_IMG (TILES_PER_IMG / TILES_PER_BLOCK)  // 196
#define TOTAL_BLOCKS (BATCH * BLOCKS_PER_IMG)             // 3136
#define NXCD 8
#define BLOCKS_PER_XCD (TOTAL_BLOCKS / NXCD)              // 392 (exact -> bijective)

// clang native vector type: required by __builtin_nontemporal_store
typedef float f32x4 __attribute__((ext_vector_type(4)));

__global__ __launch_bounds__(256, 3) void bilinear_proj_kernel(
    const float* __restrict__ X,      // (B, HIN, WIN, CH)
    const float* __restrict__ Tm,     // (B, 9)
    float* __restrict__ out)          // (B, OUTH, OUTW, CH)
{
    const int lane = threadIdx.x & 15;   // channel group: 4 floats each
    const int slot = threadIdx.x >> 4;   // 0..15: column slot within tile

    // XCD-contiguous swizzle (3136 % 8 == 0 -> simple form is bijective)
    const int lb = (blockIdx.x % NXCD) * BLOCKS_PER_XCD + blockIdx.x / NXCD;

    const int b        = lb / BLOCKS_PER_IMG;   // block-uniform -> scalar
    const int blkInImg = lb % BLOCKS_PER_IMG;

    const float* t = Tm + b * 9;
    const float t0 = t[0], t1 = t[1], t2 = t[2];
    const float t3 = t[3], t4 = t[4], t5 = t[5];
    const float t6 = t[6], t7 = t[7], t8 = t[8];

    const int c = lane * 4;
    const float* Xb   = X + (size_t)b * (size_t)(HIN * WIN) * CH + c;
    float*       outB = out + (size_t)b * (size_t)(OUTH * OUTW) * CH + c;

    for (int i = 0; i < TILES_PER_BLOCK; ++i) {
        const int tile   = blkInImg * TILES_PER_BLOCK + i;  // 0..783 (uniform)
        const int r      = tile / COLTILES;                  // row-pair 0..111
        const int cIdx   = tile - r * COLTILES;              // 0..6
        const int oyBase = r * 2;
        const int ox0    = cIdx * TILE_COLS;

        // 4 pixels per thread: (oyBase+py, ox0+slot+16*px), py,px in {0,1}
        float wa[4], wb[4], wc[4], wd[4];
        const f32x4* pa[4];
        const f32x4* pb[4];
        const f32x4* pc[4];
        const f32x4* pd[4];
        f32x4* po[4];

        #pragma unroll
        for (int k = 0; k < 4; ++k) {
            const int py = k >> 1;
            const int px = k & 1;
            const int oy = oyBase + py;
            const int ox = ox0 + slot + px * 16;

            // regular grid in [-1,1], linspace with N points: step = 2/(N-1)
            const float xc = -1.0f + (float)ox * (2.0f / (float)(OUTW - 1));
            const float yc = -1.0f + (float)oy * (2.0f / (float)(OUTH - 1));

            const float s0 = t0 * xc + t1 * yc + t2;
            const float s1 = t3 * xc + t4 * yc + t5;
            const float s2 = t6 * xc + t7 * yc + t8;
            const float z  = s2 + 1e-6f;
            float x = s0 / z;
            float y = s1 / z;
            x = 0.5f * (x + 1.0f) * (float)WIN;  // scaled by W, not W-1 (matches ref)
            y = 0.5f * (y + 1.0f) * (float)HIN;

            // trunc toward zero (C cast == astype(int32))
            int x0 = (int)x;
            int x1 = x0 + 1;
            int y0 = (int)y;
            int y1 = y0 + 1;
            x0 = min(max(x0, 0), WIN - 1);
            x1 = min(max(x1, 0), WIN - 1);
            y0 = min(max(y0, 0), HIN - 1);
            y1 = min(max(y1, 0), HIN - 1);

            // weights from CLIPPED int coords vs unclipped float coords (matches ref)
            const float x0f = (float)x0, x1f = (float)x1;
            const float y0f = (float)y0, y1f = (float)y1;
            wa[k] = (x1f - x) * (y1f - y);
            wb[k] = (x1f - x) * (y - y0f);
            wc[k] = (x - x0f) * (y1f - y);
            wd[k] = (x - x0f) * (y - y0f);

            pa[k] = (const f32x4*)(Xb + (size_t)(y0 * WIN + x0) * CH);
            pb[k] = (const f32x4*)(Xb + (size_t)(y1 * WIN + x0) * CH);
            pc[k] = (const f32x4*)(Xb + (size_t)(y0 * WIN + x1) * CH);
            pd[k] = (const f32x4*)(Xb + (size_t)(y1 * WIN + x1) * CH);
            po[k] = (f32x4*)(outB + (size_t)(oy * OUTW + ox) * CH);
        }

        // Phase 2: 16 independent loads in flight (deep MLP per thread)
        f32x4 va[4], vb[4], vc[4], vd[4];
        #pragma unroll
        for (int k = 0; k < 4; ++k) {
            va[k] = *pa[k];
            vb[k] = *pb[k];
            vc[k] = *pc[k];
            vd[k] = *pd[k];
        }

        // Phase 3: blend + nontemporal store (output never re-read)
        #pragma unroll
        for (int k = 0; k < 4; ++k) {
            f32x4 o = wa[k] * va[k] + wb[k] * vb[k] + wc[k] * vc[k] + wd[k] * vd[k];
            __builtin_nontemporal_store(o, po[k]);
        }
    }
}

extern "C" void kernel_launch(void* const* d_in, const int* in_sizes, int n_in,
                              void* d_out, int out_size, void* d_ws, size_t ws_size,
                              hipStream_t stream) {
    const float* X  = (const float*)d_in[0];
    const float* Tm = (const float*)d_in[1];
    float* out      = (float*)d_out;

    bilinear_proj_kernel<<<TOTAL_BLOCKS, 256, 0, stream>>>(X, Tm, out);
}